// Round 1
// baseline (12616.283 us; speedup 1.0000x reference)
//
#include <hip/hip_runtime.h>
#include <math.h>

// Model dims
#define HD 256
#define ED 300
#define BD 64
#define SD 64
#define TD 32
#define VD 32000

// ---------------- generic transpose: in[R][K] -> out[K][R] ----------------
__global__ void k_transpose(const float* __restrict__ in, float* __restrict__ out, int R, int K) {
    int i = blockIdx.x * 256 + threadIdx.x;
    if (i < R * K) {
        int r = i / K, k = i - r * K;
        out[(size_t)k * R + r] = in[i];
    }
}

// ---------------- embedding gather: x[(s*64+b)*300 + k] = fr_emb[fr[b][s]][k] ----------------
__global__ void k_emb(const int* __restrict__ fr, const float* __restrict__ emb, float* __restrict__ x) {
    int i = blockIdx.x * 256 + threadIdx.x;
    if (i < 4096 * 300) {
        int m = i / 300, k = i - m * 300;
        int s = m >> 6, b = m & 63;
        int tok = fr[b * 64 + s];
        x[i] = emb[(size_t)tok * 300 + k];
    }
}

// ---------------- generic fp32 GEMM: C[M][N] = A[M][K] @ B[N][K]^T + bias[N] ----------------
// M, N multiples of 64; K arbitrary (zero-padded in tiles).
__launch_bounds__(256)
__global__ void k_gemm(const float* __restrict__ A, const float* __restrict__ B,
                       const float* __restrict__ bias, float* __restrict__ C,
                       int M, int N, int K) {
    __shared__ float As[16][68];   // +4 pad: kills 16-way bank conflict on transposed store
    __shared__ float Bs[16][68];
    int tid = threadIdx.x;
    int m0 = blockIdx.x * 64;
    int n0 = blockIdx.y * 64;
    int tx = tid & 15, ty = tid >> 4;
    float acc[4][4] = {};
    for (int k0 = 0; k0 < K; k0 += 16) {
        for (int e = tid; e < 1024; e += 256) {
            int mm = e >> 4, kk = e & 15;
            int k = k0 + kk;
            As[kk][mm] = (k < K) ? A[(size_t)(m0 + mm) * K + k] : 0.f;
        }
        for (int e = tid; e < 1024; e += 256) {
            int nn = e >> 4, kk = e & 15;
            int k = k0 + kk;
            Bs[kk][nn] = (k < K) ? B[(size_t)(n0 + nn) * K + k] : 0.f;
        }
        __syncthreads();
#pragma unroll
        for (int kk = 0; kk < 16; ++kk) {
            float4 a4 = *(const float4*)&As[kk][ty * 4];
            float4 b4 = *(const float4*)&Bs[kk][tx * 4];
            float av[4] = {a4.x, a4.y, a4.z, a4.w};
            float bv[4] = {b4.x, b4.y, b4.z, b4.w};
#pragma unroll
            for (int i = 0; i < 4; ++i)
#pragma unroll
                for (int j = 0; j < 4; ++j)
                    acc[i][j] += av[i] * bv[j];
        }
        __syncthreads();
    }
#pragma unroll
    for (int i = 0; i < 4; ++i) {
        int m = m0 + ty * 4 + i;
#pragma unroll
        for (int j = 0; j < 4; ++j) {
            int n = n0 + tx * 4 + j;
            C[(size_t)m * N + n] = acc[i][j] + (bias ? bias[n] : 0.f);
        }
    }
}

// ---------------- encoder GRU recurrence (one layer, both directions) ----------------
// grid 64 blocks x 512 threads. block: d = bx>>5 (0=fwd,1=bwd), handles batch b0, b0+1.
// gi:   [s*64+b][1536]  (col = d*768 + gate*256 + j), includes bih
// whh_t:[k(256)][1536]  (col = d*768 + row)
// bhh:  [2][768] flat
// ys:   [s*64+b][512]   (col = d*256 + j)
// hfin: [d*64+b][256]
__launch_bounds__(512)
__global__ void k_rec(const float* __restrict__ gi, const float* __restrict__ whh_t,
                      const float* __restrict__ bhh, float* __restrict__ ys,
                      float* __restrict__ hfin) {
    __shared__ float h[2][256];
    __shared__ float part[2][3][256];
    int tid = threadIdx.x;
    int d = blockIdx.x >> 5;
    int b0 = (blockIdx.x & 31) * 2;
    h[tid >> 8][tid & 255] = 0.f;
    __syncthreads();
    int lb = 0, g = 0, qj = 0;
    bool qact = tid < 384;
    if (qact) { lb = tid / 192; int q = tid % 192; g = q >> 6; qj = q & 63; }
    const float* wp = whh_t + (size_t)d * 768 + g * 256 + qj * 4;

    for (int step = 0; step < 64; ++step) {
        int s = d ? (63 - step) : step;
        if (qact) {
            float a0 = 0.f, a1 = 0.f, a2 = 0.f, a3 = 0.f;
            const float* hp = h[lb];
#pragma unroll 4
            for (int k = 0; k < 256; ++k) {
                float4 w4 = *(const float4*)(wp + (size_t)k * 1536);
                float hk = hp[k];
                a0 += w4.x * hk; a1 += w4.y * hk; a2 += w4.z * hk; a3 += w4.w * hk;
            }
            part[lb][g][qj * 4 + 0] = a0;
            part[lb][g][qj * 4 + 1] = a1;
            part[lb][g][qj * 4 + 2] = a2;
            part[lb][g][qj * 4 + 3] = a3;
        }
        __syncthreads();
        {
            int plb = tid >> 8, j = tid & 255;
            int b = b0 + plb;
            const float* gib = gi + (size_t)(s * 64 + b) * 1536 + d * 768;
            float gr = part[plb][0][j] + bhh[d * 768 + j];
            float gz = part[plb][1][j] + bhh[d * 768 + 256 + j];
            float gn = part[plb][2][j] + bhh[d * 768 + 512 + j];
            float r = 1.f / (1.f + expf(-(gib[j] + gr)));
            float z = 1.f / (1.f + expf(-(gib[256 + j] + gz)));
            float n = tanhf(gib[512 + j] + r * gn);
            float hv = h[plb][j];
            float hn = (1.f - z) * n + z * hv;
            ys[(size_t)(s * 64 + b) * 512 + d * 256 + j] = hn;
            if (step == 63) hfin[(size_t)(d * 64 + b) * 256 + j] = hn;
            h[plb][j] = hn;   // own element only; all cross-reads done before barrier above
        }
        __syncthreads();
    }
}

// ---------------- pack hidden for the (exact) reference reshape(2,B,2H) ----------------
// A[l*64+b2][c] = hfin_l[(d*64 + b)*256 + h], d=b2>>5, b=2*(b2&31)+(c>>8), h=c&255
__global__ void k_hpack(const float* __restrict__ hf0, const float* __restrict__ hf1,
                        float* __restrict__ A) {
    int i = blockIdx.x * 256 + threadIdx.x;
    if (i < 128 * 512) {
        int m = i >> 9, c = i & 511;
        int l = m >> 6, b2 = m & 63;
        int d = b2 >> 5;
        int b = 2 * (b2 & 31) + (c >> 8);
        int hh = c & 255;
        const float* src = l ? hf1 : hf0;
        A[i] = src[(size_t)(d * 64 + b) * 256 + hh];
    }
}

// ---------------- fused decoder step (everything except logits): 1 block per batch ----------------
__launch_bounds__(256)
__global__ void k_dec1(int t,
                       const float* __restrict__ pval, const int* __restrict__ pidx,
                       const float* __restrict__ en_emb,
                       const float* __restrict__ attn_w, const float* __restrict__ attn_b,
                       const float* __restrict__ tot_w, const float* __restrict__ tot_b,
                       const float* __restrict__ te, const float* __restrict__ enc,
                       const float* __restrict__ rnnT_w, const float* __restrict__ rnnT_b,
                       const float* __restrict__ d0_wih, const float* __restrict__ d0_whh,
                       const float* __restrict__ d0_bih, const float* __restrict__ d0_bhh,
                       const float* __restrict__ d1_wih, const float* __restrict__ d1_whh,
                       const float* __restrict__ d1_bih, const float* __restrict__ d1_bhh,
                       float* __restrict__ hdec) {
    int b = blockIdx.x;
    int tid = threadIdx.x;
    __shared__ float seqv[304];
    __shared__ float hq[256];
    __shared__ float h0[256];
    __shared__ float aq[256];
    __shared__ float scred[64][4];
    __shared__ float sc[64];
    __shared__ float attnv[64];
    __shared__ float wsum[512];
    __shared__ float xt[304];
    __shared__ float h0n[256];
    __shared__ int tok_s;

    // Phase A: token from previous step's partial argmax (t=0 -> BOS=1)
    if (t == 0) {
        if (tid == 0) tok_s = 1;
    } else if (tid < 64) {
        float v = -INFINITY; int idx = 0x7fffffff;
        if (tid < 63) { v = pval[b * 64 + tid]; idx = pidx[b * 64 + tid]; }
        for (int off = 32; off > 0; off >>= 1) {
            float v2 = __shfl_down(v, off);
            int i2 = __shfl_down(idx, off);
            if (v2 > v || (v2 == v && i2 < idx)) { v = v2; idx = i2; }
        }
        if (tid == 0) tok_s = idx;
    }
    __syncthreads();
    int tok = tok_s;
    for (int e = tid; e < 300; e += 256) seqv[e] = en_emb[(size_t)tok * 300 + e];
    hq[tid] = hdec[(size_t)(64 + b) * 256 + tid];
    h0[tid] = hdec[(size_t)b * 256 + tid];
    __syncthreads();

    // Phase B: attn_q[j] = attn_b[j] + attn_w[j,:] . hq
    {
        float acc = attn_b[tid];
        const float* wr = attn_w + (size_t)tid * 256;
#pragma unroll 4
        for (int k = 0; k < 256; k += 4) {
            float4 w4 = *(const float4*)(wr + k);
            float4 h4 = *(const float4*)&hq[k];
            acc += w4.x * h4.x + w4.y * h4.y + w4.z * h4.z + w4.w * h4.w;
        }
        aq[tid] = acc;
    }
    __syncthreads();

    // Phase C: scores[s] = tot_b + sum_j tot_w[j] * tanh(te[s,b,j] + aq[j])
    {
        int s = tid >> 2, p = tid & 3;
        const float* tep = te + (size_t)(s * 64 + b) * 256 + p * 64;
        float acc = 0.f;
        for (int jj = 0; jj < 64; ++jj)
            acc += tot_w[p * 64 + jj] * tanhf(tep[jj] + aq[p * 64 + jj]);
        scred[s][p] = acc;
    }
    __syncthreads();
    if (tid < 64) sc[tid] = scred[tid][0] + scred[tid][1] + scred[tid][2] + scred[tid][3] + tot_b[0];
    __syncthreads();

    // Phase D: softmax over s (one wave)
    if (tid < 64) {
        float v = sc[tid];
        float m = v;
        for (int off = 32; off > 0; off >>= 1) m = fmaxf(m, __shfl_xor(m, off));
        float e = expf(v - m);
        float sum = e;
        for (int off = 32; off > 0; off >>= 1) sum += __shfl_xor(sum, off);
        attnv[tid] = e / sum;
    }
    __syncthreads();

    // Phase E: weighted[c] = sum_s attn[s] * enc[s,b,c]
    for (int c = tid; c < 512; c += 256) {
        float acc = 0.f;
        for (int s = 0; s < 64; ++s) acc += attnv[s] * enc[(size_t)(s * 64 + b) * 512 + c];
        wsum[c] = acc;
    }
    __syncthreads();

    // Phase F: xt[e] = rnnT_b[e] + rnnT_w[e,0:512].wsum + rnnT_w[e,512:812].seq
    for (int e = tid; e < 300; e += 256) {
        float acc = rnnT_b[e];
        const float* wr = rnnT_w + (size_t)e * 812;
#pragma unroll 4
        for (int c = 0; c < 512; c += 4) {
            float4 w4 = *(const float4*)(wr + c);
            float4 s4 = *(const float4*)&wsum[c];
            acc += w4.x * s4.x + w4.y * s4.y + w4.z * s4.z + w4.w * s4.w;
        }
#pragma unroll 4
        for (int c = 0; c < 300; c += 4) {
            float4 w4 = *(const float4*)(wr + 512 + c);
            float4 s4 = *(const float4*)&seqv[c];
            acc += w4.x * s4.x + w4.y * s4.y + w4.z * s4.z + w4.w * s4.w;
        }
        xt[e] = acc;
    }
    __syncthreads();

    // Phase G: h0' = GRU(xt, h0; dec0)
    {
        int j = tid;
        float g0 = d0_bih[j], g1 = d0_bih[256 + j], g2 = d0_bih[512 + j];
#pragma unroll 2
        for (int k = 0; k < 300; k += 4) {
            float4 x4 = *(const float4*)&xt[k];
            float4 wa = *(const float4*)&d0_wih[(size_t)j * 300 + k];
            float4 wb = *(const float4*)&d0_wih[(size_t)(256 + j) * 300 + k];
            float4 wc = *(const float4*)&d0_wih[(size_t)(512 + j) * 300 + k];
            g0 += wa.x * x4.x + wa.y * x4.y + wa.z * x4.z + wa.w * x4.w;
            g1 += wb.x * x4.x + wb.y * x4.y + wb.z * x4.z + wb.w * x4.w;
            g2 += wc.x * x4.x + wc.y * x4.y + wc.z * x4.z + wc.w * x4.w;
        }
        float r0 = d0_bhh[j], r1 = d0_bhh[256 + j], r2 = d0_bhh[512 + j];
#pragma unroll 2
        for (int k = 0; k < 256; k += 4) {
            float4 h4 = *(const float4*)&h0[k];
            float4 wa = *(const float4*)&d0_whh[(size_t)j * 256 + k];
            float4 wb = *(const float4*)&d0_whh[(size_t)(256 + j) * 256 + k];
            float4 wc = *(const float4*)&d0_whh[(size_t)(512 + j) * 256 + k];
            r0 += wa.x * h4.x + wa.y * h4.y + wa.z * h4.z + wa.w * h4.w;
            r1 += wb.x * h4.x + wb.y * h4.y + wb.z * h4.z + wb.w * h4.w;
            r2 += wc.x * h4.x + wc.y * h4.y + wc.z * h4.z + wc.w * h4.w;
        }
        float r = 1.f / (1.f + expf(-(g0 + r0)));
        float z = 1.f / (1.f + expf(-(g1 + r1)));
        float n = tanhf(g2 + r * r2);
        float hnv = (1.f - z) * n + z * h0[j];
        hdec[(size_t)b * 256 + j] = hnv;
        h0n[j] = hnv;
    }
    __syncthreads();

    // Phase H: h1' = GRU(h0', hq; dec1)
    {
        int j = tid;
        float g0 = d1_bih[j], g1 = d1_bih[256 + j], g2 = d1_bih[512 + j];
#pragma unroll 2
        for (int k = 0; k < 256; k += 4) {
            float4 x4 = *(const float4*)&h0n[k];
            float4 wa = *(const float4*)&d1_wih[(size_t)j * 256 + k];
            float4 wb = *(const float4*)&d1_wih[(size_t)(256 + j) * 256 + k];
            float4 wc = *(const float4*)&d1_wih[(size_t)(512 + j) * 256 + k];
            g0 += wa.x * x4.x + wa.y * x4.y + wa.z * x4.z + wa.w * x4.w;
            g1 += wb.x * x4.x + wb.y * x4.y + wb.z * x4.z + wb.w * x4.w;
            g2 += wc.x * x4.x + wc.y * x4.y + wc.z * x4.z + wc.w * x4.w;
        }
        float r0 = d1_bhh[j], r1 = d1_bhh[256 + j], r2 = d1_bhh[512 + j];
#pragma unroll 2
        for (int k = 0; k < 256; k += 4) {
            float4 h4 = *(const float4*)&hq[k];
            float4 wa = *(const float4*)&d1_whh[(size_t)j * 256 + k];
            float4 wb = *(const float4*)&d1_whh[(size_t)(256 + j) * 256 + k];
            float4 wc = *(const float4*)&d1_whh[(size_t)(512 + j) * 256 + k];
            r0 += wa.x * h4.x + wa.y * h4.y + wa.z * h4.z + wa.w * h4.w;
            r1 += wb.x * h4.x + wb.y * h4.y + wb.z * h4.z + wb.w * h4.w;
            r2 += wc.x * h4.x + wc.y * h4.y + wc.z * h4.z + wc.w * h4.w;
        }
        float r = 1.f / (1.f + expf(-(g0 + r0)));
        float z = 1.f / (1.f + expf(-(g1 + r1)));
        float n = tanhf(g2 + r * r2);
        float hnv = (1.f - z) * n + z * hq[j];
        hdec[(size_t)(64 + b) * 256 + j] = hnv;
    }
}

// ---------------- logits + write out + partial argmax ----------------
// grid (63, 8): vb covers 512 vocab (2/thread), bc covers 8 batch
__launch_bounds__(256)
__global__ void k_dec2(int t, const float* __restrict__ voc_w, const float* __restrict__ voc_b,
                       const float* __restrict__ hdec, float* __restrict__ out,
                       float* __restrict__ pval, int* __restrict__ pidx) {
    int vb = blockIdx.x, bc = blockIdx.y;
    int tid = threadIdx.x;
    int v0 = vb * 512;
    int b0 = bc * 8;
    __shared__ float hl[8][256];
    __shared__ float rv[256];
    __shared__ int ri[256];
    for (int e = tid; e < 2048; e += 256) {
        int bb = e >> 8, k = e & 255;
        hl[bb][k] = hdec[(size_t)(64 + b0 + bb) * 256 + k];
    }
    __syncthreads();
    int v1 = v0 + tid;
    int v2 = v0 + 256 + tid;
    bool has2 = v2 < VD;
    float acc1[8], acc2[8];
    float b1v = voc_b[v1];
    float b2v = has2 ? voc_b[v2] : 0.f;
#pragma unroll
    for (int bb = 0; bb < 8; ++bb) { acc1[bb] = b1v; acc2[bb] = b2v; }
    for (int k = 0; k < 256; k += 4) {
        float4 w1 = *(const float4*)&voc_w[(size_t)v1 * 256 + k];
        float4 w2 = make_float4(0.f, 0.f, 0.f, 0.f);
        if (has2) w2 = *(const float4*)&voc_w[(size_t)v2 * 256 + k];
#pragma unroll
        for (int bb = 0; bb < 8; ++bb) {
            float4 h4 = *(const float4*)&hl[bb][k];
            acc1[bb] += w1.x * h4.x + w1.y * h4.y + w1.z * h4.z + w1.w * h4.w;
            acc2[bb] += w2.x * h4.x + w2.y * h4.y + w2.z * h4.z + w2.w * h4.w;
        }
    }
    for (int bb = 0; bb < 8; ++bb) {
        int b = b0 + bb;
        out[((size_t)b * 32 + t) * VD + v1] = acc1[bb];
        if (has2) out[((size_t)b * 32 + t) * VD + v2] = acc2[bb];
        float bv = acc1[bb]; int bi = v1;
        if (has2 && (acc2[bb] > bv)) { bv = acc2[bb]; bi = v2; }  // tie -> lower idx (v1)
        rv[tid] = bv; ri[tid] = bi;
        __syncthreads();
        for (int stn = 128; stn > 0; stn >>= 1) {
            if (tid < stn) {
                float ov = rv[tid + stn]; int oi = ri[tid + stn];
                if (ov > rv[tid] || (ov == rv[tid] && oi < ri[tid])) { rv[tid] = ov; ri[tid] = oi; }
            }
            __syncthreads();
        }
        if (tid == 0) { pval[(size_t)b * 64 + vb] = rv[0]; pidx[(size_t)b * 64 + vb] = ri[0]; }
        __syncthreads();
    }
}

// ---------------- host ----------------
extern "C" void kernel_launch(void* const* d_in, const int* in_sizes, int n_in,
                              void* d_out, int out_size, void* d_ws, size_t ws_size,
                              hipStream_t stream) {
    (void)in_sizes; (void)n_in; (void)out_size; (void)ws_size;
    const int*   fr     = (const int*)  d_in[0];
    const float* fr_emb = (const float*)d_in[1];
    const float* en_emb = (const float*)d_in[2];
    const float* e0_wih = (const float*)d_in[3];
    const float* e0_whh = (const float*)d_in[4];
    const float* e0_bih = (const float*)d_in[5];
    const float* e0_bhh = (const float*)d_in[6];
    const float* e1_wih = (const float*)d_in[7];
    const float* e1_whh = (const float*)d_in[8];
    const float* e1_bih = (const float*)d_in[9];
    const float* e1_bhh = (const float*)d_in[10];
    const float* d0_wih = (const float*)d_in[11];
    const float* d0_whh = (const float*)d_in[12];
    const float* d0_bih = (const float*)d_in[13];
    const float* d0_bhh = (const float*)d_in[14];
    const float* d1_wih = (const float*)d_in[15];
    const float* d1_whh = (const float*)d_in[16];
    const float* d1_bih = (const float*)d_in[17];
    const float* d1_bhh = (const float*)d_in[18];
    const float* hid_w  = (const float*)d_in[19];
    const float* hid_b  = (const float*)d_in[20];
    const float* encT_w = (const float*)d_in[21];
    const float* encT_b = (const float*)d_in[22];
    const float* attn_w = (const float*)d_in[23];
    const float* attn_b = (const float*)d_in[24];
    const float* tot_w  = (const float*)d_in[25];
    const float* tot_b  = (const float*)d_in[26];
    const float* rnnT_w = (const float*)d_in[27];
    const float* rnnT_b = (const float*)d_in[28];
    const float* voc_w  = (const float*)d_in[29];
    const float* voc_b  = (const float*)d_in[30];
    float* out = (float*)d_out;

    float* ws = (float*)d_ws;
    size_t o = 0;
    auto take = [&](size_t n) { size_t r = o; o += (n + 15) & ~(size_t)15; return r; };
    float* whh0t = ws + take(256 * 1536);
    float* whh1t = ws + take(256 * 1536);
    float* xbuf  = ws + take((size_t)4096 * 300);
    float* gi    = ws + take((size_t)4096 * 1536);   // reused for layer0 and layer1
    float* ys0   = ws + take((size_t)4096 * 512);
    float* ys1   = ws + take((size_t)4096 * 512);    // = encoding
    float* te    = ws + take((size_t)4096 * 256);
    float* hfin0 = ws + take(2 * 64 * 256);
    float* hfin1 = ws + take(2 * 64 * 256);
    float* ahid  = ws + take(128 * 512);
    float* hdec  = ws + take(128 * 256);
    float* pval  = ws + take(64 * 64);
    int*   pidx  = (int*)(ws + take(64 * 64));
    // total ~11.6M floats (~46.5 MB)

    // weight transposes needed for f4 recurrence loads
    k_transpose<<<(1536 * 256 + 255) / 256, 256, 0, stream>>>(e0_whh, whh0t, 1536, 256);
    k_transpose<<<(1536 * 256 + 255) / 256, 256, 0, stream>>>(e1_whh, whh1t, 1536, 256);
    // embedding
    k_emb<<<(4096 * 300 + 255) / 256, 256, 0, stream>>>(fr, fr_emb, xbuf);
    // encoder layer 0: input projection (time-parallel) then recurrence
    k_gemm<<<dim3(64, 24), 256, 0, stream>>>(xbuf, e0_wih, e0_bih, gi, 4096, 1536, 300);
    k_rec<<<64, 512, 0, stream>>>(gi, whh0t, e0_bhh, ys0, hfin0);
    // encoder layer 1
    k_gemm<<<dim3(64, 24), 256, 0, stream>>>(ys0, e1_wih, e1_bih, gi, 4096, 1536, 512);
    k_rec<<<64, 512, 0, stream>>>(gi, whh1t, e1_bhh, ys1, hfin1);
    // trans_enc
    k_gemm<<<dim3(64, 4), 256, 0, stream>>>(ys1, encT_w, encT_b, te, 4096, 256, 512);
    // hidden init (exact reference reshape semantics)
    k_hpack<<<256, 256, 0, stream>>>(hfin0, hfin1, ahid);
    k_gemm<<<dim3(2, 4), 256, 0, stream>>>(ahid, hid_w, hid_b, hdec, 128, 256, 512);
    // decoder
    for (int t = 0; t < 32; ++t) {
        k_dec1<<<64, 256, 0, stream>>>(t, pval, pidx, en_emb, attn_w, attn_b, tot_w, tot_b,
                                       te, ys1, rnnT_w, rnnT_b,
                                       d0_wih, d0_whh, d0_bih, d0_bhh,
                                       d1_wih, d1_whh, d1_bih, d1_bhh, hdec);
        k_dec2<<<dim3(63, 8), 256, 0, stream>>>(t, voc_w, voc_b, hdec, out, pval, pidx);
    }
}

// Round 2
// 10943.426 us; speedup vs baseline: 1.1529x; 1.1529x over previous
//
#include <hip/hip_runtime.h>
#include <math.h>

#define VD 32000

__device__ __forceinline__ float dot4f(float4 a, float4 b) {
    return a.x*b.x + a.y*b.y + a.z*b.z + a.w*b.w;
}

// ---------------- embedding gather: x[(s*64+b)*300 + k] = fr_emb[fr[b][s]][k] ----------------
__global__ void k_emb(const int* __restrict__ fr, const float* __restrict__ emb, float* __restrict__ x) {
    int i = blockIdx.x * 256 + threadIdx.x;
    if (i < 4096 * 300) {
        int m = i / 300, k = i - m * 300;
        int s = m >> 6, b = m & 63;
        int tok = fr[b * 64 + s];
        x[i] = emb[(size_t)tok * 300 + k];
    }
}

// ---------------- fp32 GEMM 128x128 tile: C[M][N] = A[M][K] @ B[N][K]^T + bias[N] ----------------
// M, N multiples of 128; K multiple of 4 (zero-padded in 16-tiles).
__launch_bounds__(256)
__global__ void k_gemm128(const float* __restrict__ A, const float* __restrict__ B,
                          const float* __restrict__ bias, float* __restrict__ C,
                          int M, int N, int K) {
    __shared__ __align__(16) float As[16][132];
    __shared__ __align__(16) float Bs[16][132];
    int tid = threadIdx.x;
    int m0 = blockIdx.x * 128;
    int n0 = blockIdx.y * 128;
    int tx = tid & 15, ty = tid >> 4;   // each thread: 8 rows (ty) x 8 cols (tx)
    float acc[8][8] = {};
    for (int k0 = 0; k0 < K; k0 += 16) {
#pragma unroll
        for (int l = 0; l < 2; ++l) {
            int e = tid + l * 256;          // 0..511
            int row = e >> 2, kc = (e & 3) << 2;
            int k = k0 + kc;
            float4 va = make_float4(0.f, 0.f, 0.f, 0.f);
            float4 vb = make_float4(0.f, 0.f, 0.f, 0.f);
            if (k < K) {
                va = *(const float4*)&A[(size_t)(m0 + row) * K + k];
                vb = *(const float4*)&B[(size_t)(n0 + row) * K + k];
            }
            As[kc + 0][row] = va.x; As[kc + 1][row] = va.y; As[kc + 2][row] = va.z; As[kc + 3][row] = va.w;
            Bs[kc + 0][row] = vb.x; Bs[kc + 1][row] = vb.y; Bs[kc + 2][row] = vb.z; Bs[kc + 3][row] = vb.w;
        }
        __syncthreads();
#pragma unroll
        for (int kk = 0; kk < 16; ++kk) {
            float a[8], bb[8];
            *(float4*)&a[0]  = *(const float4*)&As[kk][ty * 8];
            *(float4*)&a[4]  = *(const float4*)&As[kk][ty * 8 + 4];
            *(float4*)&bb[0] = *(const float4*)&Bs[kk][tx * 8];
            *(float4*)&bb[4] = *(const float4*)&Bs[kk][tx * 8 + 4];
#pragma unroll
            for (int i = 0; i < 8; ++i)
#pragma unroll
                for (int j = 0; j < 8; ++j)
                    acc[i][j] += a[i] * bb[j];
        }
        __syncthreads();
    }
#pragma unroll
    for (int i = 0; i < 8; ++i) {
        int m = m0 + ty * 8 + i;
#pragma unroll
        for (int j = 0; j < 8; j += 4) {
            int n = n0 + tx * 8 + j;
            float4 o;
            o.x = acc[i][j + 0] + (bias ? bias[n + 0] : 0.f);
            o.y = acc[i][j + 1] + (bias ? bias[n + 1] : 0.f);
            o.z = acc[i][j + 2] + (bias ? bias[n + 2] : 0.f);
            o.w = acc[i][j + 3] + (bias ? bias[n + 3] : 0.f);
            *(float4*)&C[(size_t)m * N + n] = o;
        }
    }
}

// ---------------- encoder GRU recurrence: one block per (direction, batch) ----------------
// 128 blocks x 256 threads. Thread u owns unit u: all 3 gate rows (u, 256+u, 512+u).
// gi:  [s*64+b][1536]  (col = d*768 + gate*256 + u), includes bih (from GEMM bias)
// whh: original layout [2][768][256] (row-contiguous)
__launch_bounds__(256)
__global__ void k_rec(const float* __restrict__ gi, const float* __restrict__ whh,
                      const float* __restrict__ bhh, float* __restrict__ ys,
                      float* __restrict__ hfin) {
    __shared__ __align__(16) float h[256];
    int u = threadIdx.x;
    int d = blockIdx.x >> 6;
    int b = blockIdx.x & 63;
    h[u] = 0.f;
    const float* wr_ = whh + ((size_t)d * 768 + u) * 256;
    const float* wz_ = wr_ + 256 * 256;
    const float* wn_ = wr_ + 512 * 256;
    float br = bhh[d * 768 + u];
    float bz = bhh[d * 768 + 256 + u];
    float bn = bhh[d * 768 + 512 + u];
    __syncthreads();
    for (int step = 0; step < 64; ++step) {
        int s = d ? (63 - step) : step;
        float ar = 0.f, az = 0.f, an_ = 0.f;
#pragma unroll 4
        for (int k = 0; k < 256; k += 4) {
            float4 hv = *(const float4*)&h[k];
            float4 w0 = *(const float4*)&wr_[k];
            float4 w1 = *(const float4*)&wz_[k];
            float4 w2 = *(const float4*)&wn_[k];
            ar  += dot4f(w0, hv);
            az  += dot4f(w1, hv);
            an_ += dot4f(w2, hv);
        }
        const float* gib = gi + (size_t)(s * 64 + b) * 1536 + d * 768;
        float hv_old = h[u];
        float r = 1.f / (1.f + expf(-(gib[u] + ar + br)));
        float z = 1.f / (1.f + expf(-(gib[256 + u] + az + bz)));
        float n = tanhf(gib[512 + u] + r * (an_ + bn));
        float hn = (1.f - z) * n + z * hv_old;
        __syncthreads();             // all reads of h complete before overwrite
        h[u] = hn;
        ys[(size_t)(s * 64 + b) * 512 + d * 256 + u] = hn;
        if (step == 63) hfin[(size_t)(d * 64 + b) * 256 + u] = hn;
        __syncthreads();
    }
}

// ---------------- pack hidden for the (exact) reference reshape(2,B,2H) ----------------
__global__ void k_hpack(const float* __restrict__ hf0, const float* __restrict__ hf1,
                        float* __restrict__ A) {
    int i = blockIdx.x * 256 + threadIdx.x;
    if (i < 128 * 512) {
        int m = i >> 9, c = i & 511;
        int l = m >> 6, b2 = m & 63;
        int d = b2 >> 5;
        int b = 2 * (b2 & 31) + (c >> 8);
        int hh = c & 255;
        const float* src = l ? hf1 : hf0;
        A[i] = src[(size_t)(d * 64 + b) * 256 + hh];
    }
}

// ---------------- fused decoder step (all but logits): 1 block/batch, 1024 threads ----------------
__launch_bounds__(1024)
__global__ void k_dec1(int t,
                       const float* __restrict__ pval, const int* __restrict__ pidx,
                       const float* __restrict__ en_emb,
                       const float* __restrict__ attn_w, const float* __restrict__ attn_b,
                       const float* __restrict__ tot_w, const float* __restrict__ tot_b,
                       const float* __restrict__ te, const float* __restrict__ enc,
                       const float* __restrict__ rnnT_w, const float* __restrict__ rnnT_b,
                       const float* __restrict__ d0_wih, const float* __restrict__ d0_whh,
                       const float* __restrict__ d0_bih, const float* __restrict__ d0_bhh,
                       const float* __restrict__ d1_wih, const float* __restrict__ d1_whh,
                       const float* __restrict__ d1_bih, const float* __restrict__ d1_bhh,
                       float* __restrict__ hdec) {
    int b = blockIdx.x;
    int tid = threadIdx.x;
    __shared__ __align__(16) float cat[816];    // [0,512)=weighted, [512,812)=seq emb
    __shared__ __align__(16) float hq[256];
    __shared__ __align__(16) float h0[256];
    __shared__ __align__(16) float aq[256];
    __shared__ __align__(16) float xt[304];
    __shared__ __align__(16) float fpart[3][304];
    __shared__ __align__(16) float gih[768];
    __shared__ __align__(16) float ghh[768];
    __shared__ __align__(16) float h0n[256];
    __shared__ float sc[64];
    __shared__ float attnv[64];
    __shared__ float wv[16];
    __shared__ int   wi[16];
    __shared__ int   tok_s;

    // Phase A: finish argmax over previous step's 1000 partials (t=0 -> BOS=1)
    if (t == 0) {
        if (tid == 0) tok_s = 1;
    } else {
        float v = -INFINITY; int idx = 0x7fffffff;
        if (tid < 1000) { v = pval[(size_t)b * 1024 + tid]; idx = pidx[(size_t)b * 1024 + tid]; }
#pragma unroll
        for (int off = 32; off > 0; off >>= 1) {
            float v2 = __shfl_down(v, off); int i2 = __shfl_down(idx, off);
            if (v2 > v || (v2 == v && i2 < idx)) { v = v2; idx = i2; }
        }
        if ((tid & 63) == 0) { wv[tid >> 6] = v; wi[tid >> 6] = idx; }
    }
    __syncthreads();
    if (t > 0 && tid < 16) {
        float v = wv[tid]; int idx = wi[tid];
#pragma unroll
        for (int off = 8; off > 0; off >>= 1) {
            float v2 = __shfl_down(v, off); int i2 = __shfl_down(idx, off);
            if (v2 > v || (v2 == v && i2 < idx)) { v = v2; idx = i2; }
        }
        if (tid == 0) tok_s = idx;
    }
    __syncthreads();
    int tok = tok_s;
    if (tid < 300) cat[512 + tid] = en_emb[(size_t)tok * 300 + tid];
    if (tid >= 512 && tid < 768) hq[tid - 512] = hdec[(size_t)(64 + b) * 256 + (tid - 512)];
    if (tid >= 768) h0[tid - 768] = hdec[(size_t)b * 256 + (tid - 768)];
    __syncthreads();

    // Phase B: aq[j] = attn_b[j] + attn_w[j,:].hq  (4-way k-split)
    {
        int j = tid >> 2, kq = tid & 3;
        const float* wr = attn_w + (size_t)j * 256 + kq * 64;
        const float* hp = hq + kq * 64;
        float acc = 0.f;
#pragma unroll
        for (int k = 0; k < 64; k += 4)
            acc += dot4f(*(const float4*)&wr[k], *(const float4*)&hp[k]);
        acc += __shfl_xor(acc, 1);
        acc += __shfl_xor(acc, 2);
        if (kq == 0) aq[j] = acc + attn_b[j];
    }
    __syncthreads();

    // Phase C: sc[s] = tot_b + sum_j tot_w[j]*tanh(te[s,b,j] + aq[j])  (16-way j-split)
    {
        int s = tid >> 4, p = tid & 15;
        const float* tep = te + (size_t)(s * 64 + b) * 256 + p * 16;
        const float* aqp = aq + p * 16;
        const float* twp = tot_w + p * 16;
        float acc = 0.f;
#pragma unroll
        for (int jj = 0; jj < 16; ++jj)
            acc += twp[jj] * tanhf(tep[jj] + aqp[jj]);
#pragma unroll
        for (int off = 8; off > 0; off >>= 1) acc += __shfl_xor(acc, off);
        if (p == 0) sc[s] = acc + tot_b[0];
    }
    __syncthreads();

    // Phase D: softmax over 64 (one wave)
    if (tid < 64) {
        float v = sc[tid];
        float m = v;
#pragma unroll
        for (int off = 32; off > 0; off >>= 1) m = fmaxf(m, __shfl_xor(m, off));
        float e = expf(v - m);
        float sum = e;
#pragma unroll
        for (int off = 32; off > 0; off >>= 1) sum += __shfl_xor(sum, off);
        attnv[tid] = e / sum;
    }
    __syncthreads();

    // Phase E: cat[c] = sum_s attn[s]*enc[s,b,c]  (2-way s-split)
    {
        int c = tid >> 1, sh = tid & 1;
        float acc = 0.f;
        int s0 = sh * 32;
#pragma unroll 8
        for (int s = s0; s < s0 + 32; ++s)
            acc += attnv[s] * enc[(size_t)(s * 64 + b) * 512 + c];
        acc += __shfl_xor(acc, 1);
        if (sh == 0) cat[c] = acc;
    }
    __syncthreads();

    // Phase F: xt[e] = rnnT_b[e] + rnnT_w[e,:].cat  (3-way k-split over 812)
    if (tid < 912) {
        int kq = tid / 304;
        int e = tid - kq * 304;
        if (e < 300) {
            int k0 = kq * 272;
            int k1 = (kq == 2) ? 812 : k0 + 272;
            const float* wr = rnnT_w + (size_t)e * 812;
            float acc = 0.f;
            for (int k = k0; k < k1; k += 4)
                acc += dot4f(*(const float4*)&wr[k], *(const float4*)&cat[k]);
            fpart[kq][e] = acc;
        }
    }
    __syncthreads();
    if (tid < 300) xt[tid] = rnnT_b[tid] + fpart[0][tid] + fpart[1][tid] + fpart[2][tid];
    __syncthreads();

    // Phase G: GRU0 gate rows (768-way row-parallel)
    if (tid < 768) {
        int j = tid;
        float gi_ = d0_bih[j];
        const float* wi_ = d0_wih + (size_t)j * 300;
#pragma unroll 5
        for (int k = 0; k < 300; k += 4)
            gi_ += dot4f(*(const float4*)&wi_[k], *(const float4*)&xt[k]);
        float gh_ = d0_bhh[j];
        const float* wh_ = d0_whh + (size_t)j * 256;
#pragma unroll 4
        for (int k = 0; k < 256; k += 4)
            gh_ += dot4f(*(const float4*)&wh_[k], *(const float4*)&h0[k]);
        gih[j] = gi_; ghh[j] = gh_;
    }
    __syncthreads();
    if (tid < 256) {
        int u = tid;
        float r = 1.f / (1.f + expf(-(gih[u] + ghh[u])));
        float z = 1.f / (1.f + expf(-(gih[256 + u] + ghh[256 + u])));
        float n = tanhf(gih[512 + u] + r * ghh[512 + u]);
        float hv = (1.f - z) * n + z * h0[u];
        hdec[(size_t)b * 256 + u] = hv;
        h0n[u] = hv;
    }
    __syncthreads();

    // Phase H: GRU1 gate rows
    if (tid < 768) {
        int j = tid;
        float gi_ = d1_bih[j];
        const float* wi_ = d1_wih + (size_t)j * 256;
#pragma unroll 4
        for (int k = 0; k < 256; k += 4)
            gi_ += dot4f(*(const float4*)&wi_[k], *(const float4*)&h0n[k]);
        float gh_ = d1_bhh[j];
        const float* wh_ = d1_whh + (size_t)j * 256;
#pragma unroll 4
        for (int k = 0; k < 256; k += 4)
            gh_ += dot4f(*(const float4*)&wh_[k], *(const float4*)&hq[k]);
        gih[j] = gi_; ghh[j] = gh_;
    }
    __syncthreads();
    if (tid < 256) {
        int u = tid;
        float r = 1.f / (1.f + expf(-(gih[u] + ghh[u])));
        float z = 1.f / (1.f + expf(-(gih[256 + u] + ghh[256 + u])));
        float n = tanhf(gih[512 + u] + r * ghh[512 + u]);
        float hv = (1.f - z) * n + z * hq[u];
        hdec[(size_t)(64 + b) * 256 + u] = hv;
    }
}

// ---------------- logits: batch-per-lane; 1000 blocks x 256 threads; 32 vocab rows/block ----------------
// lane = batch (64); wave w handles rows v0+w*8 .. +8. h1 transposed in LDS (stride 66).
__launch_bounds__(256)
__global__ void k_dec2(int t, const float* __restrict__ voc_w, const float* __restrict__ voc_b,
                       const float* __restrict__ hdec, float* __restrict__ out,
                       float* __restrict__ pval, int* __restrict__ pidx) {
    __shared__ float hlT[256 * 66];     // hlT[k*66 + b]
    __shared__ float outT[32 * 66];     // outT[vl*66 + b]
    __shared__ float pm_v[4 * 64];
    __shared__ int   pm_i[4 * 64];
    int tid = threadIdx.x;
    int bx = blockIdx.x;
    int v0 = bx * 32;
    int w = tid >> 6, lb = tid & 63;

    // load h1 (64 batches x 256) transposed
    for (int e = tid; e < 4096; e += 256) {
        int bb = e >> 6, kq = (e & 63) << 2;
        float4 hv = *(const float4*)&hdec[(size_t)(64 + bb) * 256 + kq];
        hlT[(kq + 0) * 66 + bb] = hv.x;
        hlT[(kq + 1) * 66 + bb] = hv.y;
        hlT[(kq + 2) * 66 + bb] = hv.z;
        hlT[(kq + 3) * 66 + bb] = hv.w;
    }
    __syncthreads();

    const float* wbase = voc_w + (size_t)(v0 + w * 8) * 256;
    float acc[8];
#pragma unroll
    for (int r = 0; r < 8; ++r) acc[r] = voc_b[v0 + w * 8 + r];
    for (int k = 0; k < 256; k += 4) {
        float h0_ = hlT[(k + 0) * 66 + lb];
        float h1_ = hlT[(k + 1) * 66 + lb];
        float h2_ = hlT[(k + 2) * 66 + lb];
        float h3_ = hlT[(k + 3) * 66 + lb];
#pragma unroll
        for (int r = 0; r < 8; ++r) {
            float4 w4 = *(const float4*)&wbase[(size_t)r * 256 + k];
            acc[r] += w4.x * h0_ + w4.y * h1_ + w4.z * h2_ + w4.w * h3_;
        }
    }
    // per-lane best over this wave's 8 rows (ascending v => strict > keeps lowest idx)
    float bv = acc[0]; int bi = v0 + w * 8;
#pragma unroll
    for (int r = 1; r < 8; ++r)
        if (acc[r] > bv) { bv = acc[r]; bi = v0 + w * 8 + r; }
#pragma unroll
    for (int r = 0; r < 8; ++r) outT[(w * 8 + r) * 66 + lb] = acc[r];
    pm_v[w * 64 + lb] = bv;
    pm_i[w * 64 + lb] = bi;
    __syncthreads();

    // coalesced store of logits: out[b][t][v]
    for (int e = tid; e < 2048; e += 256) {
        int bb = e >> 5, vl = e & 31;
        out[((size_t)bb * 32 + t) * VD + v0 + vl] = outT[vl * 66 + bb];
    }
    // per-batch partial argmax for this block
    if (tid < 64) {
        float v = pm_v[tid]; int idx = pm_i[tid];
#pragma unroll
        for (int ww = 1; ww < 4; ++ww) {
            float ov = pm_v[ww * 64 + tid]; int oi = pm_i[ww * 64 + tid];
            if (ov > v || (ov == v && oi < idx)) { v = ov; idx = oi; }
        }
        pval[(size_t)tid * 1024 + bx] = v;
        pidx[(size_t)tid * 1024 + bx] = idx;
    }
}

// ---------------- host ----------------
extern "C" void kernel_launch(void* const* d_in, const int* in_sizes, int n_in,
                              void* d_out, int out_size, void* d_ws, size_t ws_size,
                              hipStream_t stream) {
    (void)in_sizes; (void)n_in; (void)out_size; (void)ws_size;
    const int*   fr     = (const int*)  d_in[0];
    const float* fr_emb = (const float*)d_in[1];
    const float* en_emb = (const float*)d_in[2];
    const float* e0_wih = (const float*)d_in[3];
    const float* e0_whh = (const float*)d_in[4];
    const float* e0_bih = (const float*)d_in[5];
    const float* e0_bhh = (const float*)d_in[6];
    const float* e1_wih = (const float*)d_in[7];
    const float* e1_whh = (const float*)d_in[8];
    const float* e1_bih = (const float*)d_in[9];
    const float* e1_bhh = (const float*)d_in[10];
    const float* d0_wih = (const float*)d_in[11];
    const float* d0_whh = (const float*)d_in[12];
    const float* d0_bih = (const float*)d_in[13];
    const float* d0_bhh = (const float*)d_in[14];
    const float* d1_wih = (const float*)d_in[15];
    const float* d1_whh = (const float*)d_in[16];
    const float* d1_bih = (const float*)d_in[17];
    const float* d1_bhh = (const float*)d_in[18];
    const float* hid_w  = (const float*)d_in[19];
    const float* hid_b  = (const float*)d_in[20];
    const float* encT_w = (const float*)d_in[21];
    const float* encT_b = (const float*)d_in[22];
    const float* attn_w = (const float*)d_in[23];
    const float* attn_b = (const float*)d_in[24];
    const float* tot_w  = (const float*)d_in[25];
    const float* tot_b  = (const float*)d_in[26];
    const float* rnnT_w = (const float*)d_in[27];
    const float* rnnT_b = (const float*)d_in[28];
    const float* voc_w  = (const float*)d_in[29];
    const float* voc_b  = (const float*)d_in[30];
    float* out = (float*)d_out;

    float* ws = (float*)d_ws;
    size_t o = 0;
    auto take = [&](size_t n) { size_t r = o; o += (n + 15) & ~(size_t)15; return r; };
    float* ys0   = ws + take((size_t)4096 * 512);    // xbuf aliases the start of ys0
    float* gi    = ws + take((size_t)4096 * 1536);   // reused: layer0, layer1; then decoder bufs
    float* ys1   = ws + take((size_t)4096 * 512);    // = encoding
    float* hfin0 = ws + take(2 * 64 * 256);
    float* hfin1 = ws + take(2 * 64 * 256);
    // total ~10.6M floats (~42.2 MB)

    float* xbuf = ys0;                // live only until the layer-0 input GEMM
    // carved out of gi after the encoder finishes (gi is dead then):
    float* te   = gi;                             // 4096*256
    float* ahid = gi + (size_t)4096 * 256;        // 128*512
    float* hdec = ahid + 128 * 512;               // 128*256
    float* pval = hdec + 128 * 256;               // 64*1024
    int*   pidx = (int*)(pval + 64 * 1024);       // 64*1024

    // embedding
    k_emb<<<(4096 * 300 + 255) / 256, 256, 0, stream>>>(fr, fr_emb, xbuf);
    // encoder layer 0
    k_gemm128<<<dim3(32, 12), 256, 0, stream>>>(xbuf, e0_wih, e0_bih, gi, 4096, 1536, 300);
    k_rec<<<128, 256, 0, stream>>>(gi, e0_whh, e0_bhh, ys0, hfin0);
    // encoder layer 1
    k_gemm128<<<dim3(32, 12), 256, 0, stream>>>(ys0, e1_wih, e1_bih, gi, 4096, 1536, 512);
    k_rec<<<128, 256, 0, stream>>>(gi, e1_whh, e1_bhh, ys1, hfin1);
    // trans_enc (gi now dead; te lives in its region)
    k_gemm128<<<dim3(32, 2), 256, 0, stream>>>(ys1, encT_w, encT_b, te, 4096, 256, 512);
    // hidden init (exact reference reshape semantics)
    k_hpack<<<256, 256, 0, stream>>>(hfin0, hfin1, ahid);
    k_gemm128<<<dim3(1, 2), 256, 0, stream>>>(ahid, hid_w, hid_b, hdec, 128, 256, 512);
    // decoder
    for (int t = 0; t < 32; ++t) {
        k_dec1<<<64, 1024, 0, stream>>>(t, pval, pidx, en_emb, attn_w, attn_b, tot_w, tot_b,
                                        te, ys1, rnnT_w, rnnT_b,
                                        d0_wih, d0_whh, d0_bih, d0_bhh,
                                        d1_wih, d1_whh, d1_bih, d1_bhh, hdec);
        k_dec2<<<1000, 256, 0, stream>>>(t, voc_w, voc_b, hdec, out, pval, pidx);
    }
}